// Round 1
// baseline (5505.369 us; speedup 1.0000x reference)
//
#include <hip/hip_runtime.h>

// CSA: contextual self-attention (CotNet-style) B=4 H=W=128 C=128 heads=4 K=3
// K1: att = softmax_q( (x @ w_qkv^T) * hd^-0.5 )  -> ws [65536][324], o = head*81+p*9+q
// K2: per 8x8 tile: loop q: V_q[halo 10x10][128] = w_v[q] @ x_patch ; y += att*V (fold-gather);
//     then proj y @ w_proj^T -> out.

#define SCALE 0.17677669529663687f  // 32^-0.5

__global__ __launch_bounds__(256) void att_kernel(const float* __restrict__ x,
                                                  const float* __restrict__ w_qkv,
                                                  float* __restrict__ att,
                                                  float* __restrict__ zrow) {
  __shared__ float xl[32][128];     // 16 KB
  __shared__ float lg[32][324];     // 41.5 KB
  const int t = threadIdx.x;
  const long base = (long)blockIdx.x * 32;   // first location of this block

  if (blockIdx.x == 0 && t < 128) zrow[t] = 0.f;  // zero page for K2 OOB patches

  // stage x for 32 locations (coalesced float4)
  const float4* xsrc = (const float4*)(x + base * 128);
  for (int i = t; i < 1024; i += 256) ((float4*)&xl[0][0])[i] = xsrc[i];
  __syncthreads();

  // logits: thread owns output o, 32 accumulators over locations
  for (int ob = 0; ob < 324; ob += 256) {
    int o = ob + t;
    if (o < 324) {
      float acc[32];
#pragma unroll
      for (int li = 0; li < 32; li++) acc[li] = 0.f;
      const float4* wr = (const float4*)(w_qkv + (long)o * 128);
      for (int j4 = 0; j4 < 32; j4++) {
        float4 wv = wr[j4];
#pragma unroll
        for (int li = 0; li < 32; li++) {
          float4 xv = ((const float4*)&xl[li][0])[j4];   // wave-uniform addr: LDS broadcast
          acc[li] += wv.x * xv.x + wv.y * xv.y + wv.z * xv.z + wv.w * xv.w;
        }
      }
#pragma unroll
      for (int li = 0; li < 32; li++) lg[li][o] = acc[li];
    }
  }
  __syncthreads();

  // softmax over q within each (location, head, p) group of 9
  for (int gidx = t; gidx < 32 * 36; gidx += 256) {
    int li = gidx / 36, hp = gidx % 36;
    const float* row = &lg[li][hp * 9];
    float m = row[0];
#pragma unroll
    for (int q = 1; q < 9; q++) m = fmaxf(m, row[q]);
    float e[9], s = 0.f;
#pragma unroll
    for (int q = 0; q < 9; q++) { e[q] = __expf((row[q] - m) * SCALE); s += e[q]; }
    float inv = 1.f / s;
    float* dst = att + (base + li) * 324 + hp * 9;
#pragma unroll
    for (int q = 0; q < 9; q++) dst[q] = e[q] * inv;
  }
}

__global__ __launch_bounds__(256) void csa_kernel(const float* __restrict__ x,
                                                  const float* __restrict__ w_v,
                                                  const float* __restrict__ w_proj,
                                                  const float* __restrict__ att,
                                                  const float* __restrict__ zrow,
                                                  float* __restrict__ out) {
  __shared__ float Vq[100 * 128];   // 51.2 KB ; reused as y-tile for proj
  const int t = threadIdx.x;
  const int b = blockIdx.z;
  const int r0 = blockIdx.y * 8;
  const int c0 = blockIdx.x * 8;
  const int c = t & 127;            // channel owned by this thread
  const int g = t >> 7;             // 0/1 : which half of locations
  const int head = c >> 5;

  float yacc[32];
#pragma unroll
  for (int i = 0; i < 32; i++) yacc[i] = 0.f;

  for (int q = 0; q < 9; q++) {
    const int qi = q / 3, qj = q % 3;
    __syncthreads();  // previous iter's Vq readers done (and no-op on first iter)

    // ---- V_q for 100 halo locations (10x10), thread: channel c, 50 locations ----
    const float4* wrow = (const float4*)(w_v + ((long)q * 128 + c) * 128);
    for (int nb = 0; nb < 50; nb += 10) {
      const int n0 = g * 50 + nb;
      const float4* xptr[10];
#pragma unroll
      for (int i = 0; i < 10; i++) {
        int nn = n0 + i;
        int nr = nn / 10, nc = nn % 10;               // halo-local coords
        int gr = r0 + nr + qi - 2, gc = c0 + nc + qj - 2;  // global patch coords
        bool valid = (gr >= 0) && (gr < 128) && (gc >= 0) && (gc < 128);
        xptr[i] = valid ? (const float4*)(x + (((long)b * 128 + gr) * 128 + gc) * 128)
                        : (const float4*)zrow;        // zero padding
      }
      float acc[10];
#pragma unroll
      for (int i = 0; i < 10; i++) acc[i] = 0.f;
      for (int j4 = 0; j4 < 32; j4++) {
        float4 wv = wrow[j4];
#pragma unroll
        for (int i = 0; i < 10; i++) {
          float4 xv = xptr[i][j4];                    // wave-uniform addr, cached
          acc[i] += wv.x * xv.x + wv.y * xv.y + wv.z * xv.z + wv.w * xv.w;
        }
      }
#pragma unroll
      for (int i = 0; i < 10; i++) Vq[(n0 + i) * 128 + c] = acc[i];
    }
    __syncthreads();

    // ---- fold-gather accumulate: y[n,c] += sum_p att[n',head,p,q] * Vq[n',c] ----
    for (int k = 0; k < 32; k++) {
      int l = g * 32 + k;
      int lr = l >> 3, lc = l & 7;
      int h = r0 + lr, w = c0 + lc;
      float sum = yacc[k];
#pragma unroll
      for (int p = 0; p < 9; p++) {
        int di = p / 3, dj = p % 3;
        int hg = h + 1 - di, wg = w + 1 - dj;         // source location n'
        if (hg < 0 || hg >= 128 || wg < 0 || wg >= 128) continue;
        int nl = (hg - (r0 - 1)) * 10 + (wg - (c0 - 1));
        float a = att[((long)b * 16384 + hg * 128 + wg) * 324 + head * 81 + p * 9 + q];
        sum += a * Vq[nl * 128 + c];
      }
      yacc[k] = sum;
    }
  }
  __syncthreads();

  // ---- proj: out[n,o] = sum_c y[n,c] * w_proj[o,c] ----
  float* ylds = Vq;
#pragma unroll
  for (int k = 0; k < 32; k++) ylds[(g * 32 + k) * 128 + c] = yacc[k];
  __syncthreads();

  const float4* wp = (const float4*)(w_proj + (long)c * 128);  // c plays role of output o
  for (int k = 0; k < 32; k++) {
    int l = g * 32 + k;
    int lr = l >> 3, lc = l & 7;
    float acc = 0.f;
    const float4* yrow = (const float4*)(ylds + l * 128);
    for (int j4 = 0; j4 < 32; j4++) {
      float4 wv = wp[j4];
      float4 yv = yrow[j4];
      acc += wv.x * yv.x + wv.y * yv.y + wv.z * yv.z + wv.w * yv.w;
    }
    out[(((long)b * 128 + r0 + lr) * 128 + (c0 + lc)) * 128 + c] = acc;
  }
}

extern "C" void kernel_launch(void* const* d_in, const int* in_sizes, int n_in,
                              void* d_out, int out_size, void* d_ws, size_t ws_size,
                              hipStream_t stream) {
  const float* x      = (const float*)d_in[0];
  const float* w_qkv  = (const float*)d_in[1];
  const float* w_v    = (const float*)d_in[2];
  const float* w_proj = (const float*)d_in[3];
  float* out = (float*)d_out;
  float* att = (float*)d_ws;                       // 65536*324 fp32 = 84.9 MB
  float* zrow = att + (size_t)65536 * 324;         // 128-float zero page

  att_kernel<<<2048, 256, 0, stream>>>(x, w_qkv, att, zrow);
  dim3 g2(16, 16, 4);
  csa_kernel<<<g2, 256, 0, stream>>>(x, w_v, w_proj, att, zrow, out);
}

// Round 2
// 361.916 us; speedup vs baseline: 15.2117x; 15.2117x over previous
//
#include <hip/hip_runtime.h>

// CSA bf16-MFMA pipeline. B=4 H=W=128 C=128 heads=4 K2=9, hd=32.
// ws: xb[65536][128] bf16 | U[65536][1152] bf16 (U[n][q*128+c]=x[n]·w_v[q]^T)
//     att[65536][9][36] bf16 (att[n][q][h*9+p]) | wqkvb | wvb | wpb

typedef short bf16x8 __attribute__((ext_vector_type(8)));
typedef float f32x4  __attribute__((ext_vector_type(4)));

#define SCALE 0.17677669529663687f   // hd^-0.5

__device__ __forceinline__ unsigned short f2bf(float f) {
  unsigned u = __float_as_uint(f);
  u = (u + 0x7fffu + ((u >> 16) & 1u)) >> 16;   // RNE
  return (unsigned short)u;
}
__device__ __forceinline__ float bf2f(unsigned short s) {
  return __uint_as_float(((unsigned)s) << 16);
}
__device__ __forceinline__ bf16x8 ldsFrag(const unsigned short* p) {  // p 4B-aligned
  union { bf16x8 v; unsigned u[4]; } r;
  const unsigned* s = (const unsigned*)p;
  r.u[0] = s[0]; r.u[1] = s[1]; r.u[2] = s[2]; r.u[3] = s[3];
  return r.v;
}

// ---------------- K0: fp32 -> bf16 conversions ----------------
__global__ __launch_bounds__(256) void cvt_kernel(const float* __restrict__ x,
                                                  const float* __restrict__ wq,
                                                  const float* __restrict__ wv,
                                                  const float* __restrict__ wp,
                                                  unsigned short* __restrict__ xb,
                                                  unsigned short* __restrict__ wqb,
                                                  unsigned short* __restrict__ wvb,
                                                  unsigned short* __restrict__ wpb) {
  long i = ((long)blockIdx.x * 256 + threadIdx.x) * 4;
  if (i >= 8593920) return;
  const float* src; unsigned short* dst; long off;
  if (i < 8388608)      { src = x;  dst = xb;  off = i; }
  else if (i < 8430080) { src = wq; dst = wqb; off = i - 8388608; }
  else if (i < 8577536) { src = wv; dst = wvb; off = i - 8430080; }
  else                  { src = wp; dst = wpb; off = i - 8577536; }
  float4 v = *(const float4*)(src + off);
  ushort4 o;
  o.x = f2bf(v.x); o.y = f2bf(v.y); o.z = f2bf(v.z); o.w = f2bf(v.w);
  *(ushort4*)(dst + off) = o;
}

// ---------------- K1: att = softmax_q(x @ w_qkv^T * scale) ----------------
// grid 1024, block 256 (4 waves). M-tile 64, per-head N=81 (pad 96). LDS stride 130.
__global__ __launch_bounds__(256) void att_kernel(const unsigned short* __restrict__ xb,
                                                  const unsigned short* __restrict__ wqb,
                                                  unsigned short* __restrict__ attb) {
  __shared__ unsigned short A[64 * 130];    // 16.6 KB
  __shared__ unsigned short Bl[96 * 130];   // 25.0 KB
  __shared__ float lg[64][84];              // 21.5 KB
  const int t = threadIdx.x;
  const long m0 = (long)blockIdx.x * 64;
  for (int i = t; i < 1024; i += 256) {
    int row = i >> 4, seg = i & 15;
    const uint4 v = *(const uint4*)(xb + (m0 + row) * 128 + seg * 8);
    unsigned* d = (unsigned*)(A + row * 130 + seg * 8);
    d[0] = v.x; d[1] = v.y; d[2] = v.z; d[3] = v.w;
  }
  const int wv = t >> 6, lane = t & 63, qd = lane >> 4, l15 = lane & 15;
  __syncthreads();
  bf16x8 af[4];
#pragma unroll
  for (int kk = 0; kk < 4; kk++)
    af[kk] = ldsFrag(A + (wv * 16 + l15) * 130 + kk * 32 + qd * 8);

  for (int h = 0; h < 4; h++) {
    __syncthreads();   // prev iter's Bl/lg readers done
    for (int i = t; i < 1536; i += 256) {
      int row = i >> 4, seg = i & 15;
      uint4 v = make_uint4(0, 0, 0, 0);
      if (row < 81) v = *(const uint4*)(wqb + (long)(h * 81 + row) * 128 + seg * 8);
      unsigned* d = (unsigned*)(Bl + row * 130 + seg * 8);
      d[0] = v.x; d[1] = v.y; d[2] = v.z; d[3] = v.w;
    }
    __syncthreads();
    f32x4 acc[6] = {};
#pragma unroll
    for (int kk = 0; kk < 4; kk++)
#pragma unroll
      for (int tn = 0; tn < 6; tn++) {
        bf16x8 bf = ldsFrag(Bl + (tn * 16 + l15) * 130 + kk * 32 + qd * 8);
        acc[tn] = __builtin_amdgcn_mfma_f32_16x16x32_bf16(af[kk], bf, acc[tn], 0, 0, 0);
      }
#pragma unroll
    for (int tn = 0; tn < 6; tn++)
#pragma unroll
      for (int r = 0; r < 4; r++) {
        int col = tn * 16 + l15;                     // C/D: col=lane&15, row=quad*4+reg
        if (col < 81) lg[wv * 16 + qd * 4 + r][col] = acc[tn][r];
      }
    __syncthreads();
    for (int g = t; g < 576; g += 256) {             // 64 rows x 9 p-groups
      int row = g / 9, p = g % 9;
      const float* L = &lg[row][p * 9];
      float mx = L[0];
#pragma unroll
      for (int q = 1; q < 9; q++) mx = fmaxf(mx, L[q]);
      float e[9], s = 0.f;
#pragma unroll
      for (int q = 0; q < 9; q++) { e[q] = __expf((L[q] - mx) * SCALE); s += e[q]; }
      float inv = 1.f / s;
      unsigned short* dst = attb + (m0 + row) * 324 + h * 9 + p;
#pragma unroll
      for (int q = 0; q < 9; q++) dst[q * 36] = f2bf(e[q] * inv);
    }
  }
}

// ---------------- K2: U[n][q*128+c] = x[n] . w_v[q][c][:] ----------------
// grid 1024, block 256. A-tile (64 rows) staged once; loop q over B (w_v L2-resident).
__global__ __launch_bounds__(256) void ugemm_kernel(const unsigned short* __restrict__ xb,
                                                    const unsigned short* __restrict__ wvb,
                                                    unsigned short* __restrict__ U) {
  __shared__ unsigned short A[64 * 130];    // 16.6 KB
  __shared__ unsigned short Bl[128 * 130];  // 33.3 KB
  const int t = threadIdx.x;
  const long m0 = (long)blockIdx.x * 64;
  for (int i = t; i < 1024; i += 256) {
    int row = i >> 4, seg = i & 15;
    const uint4 v = *(const uint4*)(xb + (m0 + row) * 128 + seg * 8);
    unsigned* d = (unsigned*)(A + row * 130 + seg * 8);
    d[0] = v.x; d[1] = v.y; d[2] = v.z; d[3] = v.w;
  }
  const int wv = t >> 6, lane = t & 63, qd = lane >> 4, l15 = lane & 15;
  __syncthreads();
  bf16x8 af[4];
#pragma unroll
  for (int kk = 0; kk < 4; kk++)
    af[kk] = ldsFrag(A + (wv * 16 + l15) * 130 + kk * 32 + qd * 8);

  for (int q = 0; q < 9; q++) {
    __syncthreads();
    for (int i = t; i < 2048; i += 256) {
      int row = i >> 4, seg = i & 15;
      const uint4 v = *(const uint4*)(wvb + (long)q * 16384 + row * 128 + seg * 8);
      unsigned* d = (unsigned*)(Bl + row * 130 + seg * 8);
      d[0] = v.x; d[1] = v.y; d[2] = v.z; d[3] = v.w;
    }
    __syncthreads();
    f32x4 acc[8] = {};
#pragma unroll
    for (int kk = 0; kk < 4; kk++)
#pragma unroll
      for (int tn = 0; tn < 8; tn++) {
        bf16x8 bf = ldsFrag(Bl + (tn * 16 + l15) * 130 + kk * 32 + qd * 8);
        acc[tn] = __builtin_amdgcn_mfma_f32_16x16x32_bf16(af[kk], bf, acc[tn], 0, 0, 0);
      }
#pragma unroll
    for (int tn = 0; tn < 8; tn++)
#pragma unroll
      for (int r = 0; r < 4; r++) {
        int row = wv * 16 + qd * 4 + r;
        int col = tn * 16 + l15;
        U[(m0 + row) * 1152 + q * 128 + col] = f2bf(acc[tn][r]);
      }
  }
}

// ---------------- K3: y[n,c] = sum_pq att[n+e(p),h,p,q] * U[n+e(p)+off(q),q,c]; out = y @ wp^T ----
// grid (16,16,4), block 256: thread = (location n in 8x8 tile, head h). 
__global__ __launch_bounds__(256) void av_kernel(const unsigned short* __restrict__ U,
                                                 const unsigned short* __restrict__ attb,
                                                 const unsigned short* __restrict__ wpb,
                                                 float* __restrict__ out) {
  __shared__ unsigned short sh[24960];      // 49.9 KB, aliased across phases
  unsigned short* S  = sh;                  // [100][130] : U rows for 10x10 halo, shifted by off(q)
  unsigned short* aL = sh + 100 * 130;      // [100][36]  : att slice for q
  const int t = threadIdx.x;
  const int bb = blockIdx.z;
  const int r0 = blockIdx.y * 8, c0 = blockIdx.x * 8;
  const int n = t & 63, h = t >> 6;
  const int lr = n >> 3, lc = n & 7;
  const long nb = (long)bb * 16384;
  float y[32];
#pragma unroll
  for (int i = 0; i < 32; i++) y[i] = 0.f;

  for (int q = 0; q < 9; q++) {
    const int oqr = q / 3 - 1, oqc = q % 3 - 1;
    __syncthreads();
    for (int i = t; i < 1600; i += 256) {   // S: 100 rows x 16 chunks
      int row = i >> 4, seg = i & 15;
      int gr = r0 - 1 + row / 10 + oqr, gc = c0 - 1 + row % 10 + oqc;
      uint4 v = make_uint4(0, 0, 0, 0);
      if (gr >= 0 && gr < 128 && gc >= 0 && gc < 128)
        v = *(const uint4*)(U + (nb + gr * 128 + gc) * 1152 + q * 128 + seg * 8);
      unsigned* d = (unsigned*)(S + row * 130 + seg * 8);
      d[0] = v.x; d[1] = v.y; d[2] = v.z; d[3] = v.w;
    }
    for (int i = t; i < 1800; i += 256) {   // att: 100 rows x 18 dwords
      int row = i / 18, j = i - row * 18;
      int gr = r0 - 1 + row / 10, gc = c0 - 1 + row % 10;
      unsigned v = 0;
      if (gr >= 0 && gr < 128 && gc >= 0 && gc < 128)
        v = *(const unsigned*)(attb + (nb + gr * 128 + gc) * 324 + q * 36 + j * 2);
      *(unsigned*)(aL + row * 36 + j * 2) = v;
    }
    __syncthreads();
#pragma unroll
    for (int p = 0; p < 9; p++) {
      const int em = 1 - p / 3, ec = 1 - p % 3;
      const int ml = (lr + em + 1) * 10 + (lc + ec + 1);
      const float a = bf2f(aL[ml * 36 + h * 9 + p]);
      const unsigned* Sr = (const unsigned*)(S + ml * 130) + h * 16;
#pragma unroll
      for (int d = 0; d < 16; d++) {
        unsigned u = Sr[d];
        y[2 * d]     += a * __uint_as_float(u << 16);
        y[2 * d + 1] += a * __uint_as_float(u & 0xffff0000u);
      }
    }
  }

  // ---- proj: out[n][o] = sum_c y[n][c] * wp[o][c], via MFMA ----
  __syncthreads();                          // all S/aL readers done; re-alias LDS
  unsigned short* ybf = sh;                 // [64][130]
  unsigned short* wp  = sh + 64 * 130;      // [128][130]
  {
    unsigned* dst = (unsigned*)(ybf + n * 130) + h * 16;
#pragma unroll
    for (int d = 0; d < 16; d++)
      dst[d] = (unsigned)f2bf(y[2 * d]) | ((unsigned)f2bf(y[2 * d + 1]) << 16);
  }
  for (int i = t; i < 2048; i += 256) {
    int row = i >> 4, seg = i & 15;
    const uint4 v = *(const uint4*)(wpb + row * 128 + seg * 8);
    unsigned* d = (unsigned*)(wp + row * 130 + seg * 8);
    d[0] = v.x; d[1] = v.y; d[2] = v.z; d[3] = v.w;
  }
  __syncthreads();
  const int wv = t >> 6, lane = t & 63, qd = lane >> 4, l15 = lane & 15;
  f32x4 pacc[8] = {};
#pragma unroll
  for (int kk = 0; kk < 4; kk++) {
    bf16x8 af = ldsFrag(ybf + (wv * 16 + l15) * 130 + kk * 32 + qd * 8);
#pragma unroll
    for (int tn = 0; tn < 8; tn++) {
      bf16x8 bf = ldsFrag(wp + (tn * 16 + l15) * 130 + kk * 32 + qd * 8);
      pacc[tn] = __builtin_amdgcn_mfma_f32_16x16x32_bf16(af, bf, pacc[tn], 0, 0, 0);
    }
  }
#pragma unroll
  for (int tn = 0; tn < 8; tn++)
#pragma unroll
    for (int r = 0; r < 4; r++) {
      int nl = wv * 16 + qd * 4 + r;
      int col = tn * 16 + l15;
      out[(nb + (r0 + (nl >> 3)) * 128 + (c0 + (nl & 7))) * 128 + col] = pacc[tn][r];
    }
}

extern "C" void kernel_launch(void* const* d_in, const int* in_sizes, int n_in,
                              void* d_out, int out_size, void* d_ws, size_t ws_size,
                              hipStream_t stream) {
  const float* x  = (const float*)d_in[0];
  const float* wq = (const float*)d_in[1];
  const float* wv = (const float*)d_in[2];
  const float* wp = (const float*)d_in[3];
  char* w = (char*)d_ws;
  unsigned short* xb   = (unsigned short*)w;                               // 16,777,216 B
  unsigned short* U    = (unsigned short*)(w + 16777216);                  // 150,994,944 B
  unsigned short* attb = (unsigned short*)(w + 16777216 + 150994944);      // 42,467,328 B
  unsigned short* wqb  = (unsigned short*)(w + 16777216 + 150994944 + 42467328);
  unsigned short* wvb  = wqb + 41472;
  unsigned short* wpb  = wvb + 147456;

  cvt_kernel<<<8393, 256, 0, stream>>>(x, wq, wv, wp, xb, wqb, wvb, wpb);
  att_kernel<<<1024, 256, 0, stream>>>(xb, wqb, attb);
  ugemm_kernel<<<1024, 256, 0, stream>>>(xb, wvb, U);
  dim3 g3(16, 16, 4);
  av_kernel<<<g3, 256, 0, stream>>>(U, attb, wpb, (float*)d_out);
}

// Round 3
// 334.182 us; speedup vs baseline: 16.4742x; 1.0830x over previous
//
#include <hip/hip_runtime.h>

// CSA bf16-MFMA pipeline v3. B=4 H=W=128 C=128 heads=4 K2=9, hd=32.
// ws: xb[65536][128] | U[9][65536][128] (U[q][n][c]=x[n]·w_v[q]^T) |
//     attb[65536][9][40] (h*10+p, p=9 slot pad) | wqkvb | wvb | wpb   (all bf16)

typedef short bf16x8 __attribute__((ext_vector_type(8)));
typedef float f32x4  __attribute__((ext_vector_type(4)));
typedef float v2f    __attribute__((ext_vector_type(2)));

#define SCALE 0.17677669529663687f   // hd^-0.5

__device__ __forceinline__ unsigned short f2bf(float f) {
  unsigned u = __float_as_uint(f);
  u = (u + 0x7fffu + ((u >> 16) & 1u)) >> 16;   // RNE
  return (unsigned short)u;
}
__device__ __forceinline__ float bf2f(unsigned short s) {
  return __uint_as_float(((unsigned)s) << 16);
}
__device__ __forceinline__ bf16x8 ldsFrag(const unsigned short* p) {  // p 4B-aligned
  union { bf16x8 v; unsigned u[4]; } r;
  const unsigned* s = (const unsigned*)p;
  r.u[0] = s[0]; r.u[1] = s[1]; r.u[2] = s[2]; r.u[3] = s[3];
  return r.v;
}
__device__ __forceinline__ bf16x8 ldg8(const unsigned short* p) {     // p 16B-aligned global
  union { bf16x8 v; uint4 u; } r;
  r.u = *(const uint4*)p;
  return r.v;
}

// ---------------- K0: fp32 -> bf16 conversions ----------------
__global__ __launch_bounds__(256) void cvt_kernel(const float* __restrict__ x,
                                                  const float* __restrict__ wq,
                                                  const float* __restrict__ wv,
                                                  const float* __restrict__ wp,
                                                  unsigned short* __restrict__ xb,
                                                  unsigned short* __restrict__ wqb,
                                                  unsigned short* __restrict__ wvb,
                                                  unsigned short* __restrict__ wpb) {
  long i = ((long)blockIdx.x * 256 + threadIdx.x) * 4;
  if (i >= 8593920) return;
  const float* src; unsigned short* dst; long off;
  if (i < 8388608)      { src = x;  dst = xb;  off = i; }
  else if (i < 8430080) { src = wq; dst = wqb; off = i - 8388608; }
  else if (i < 8577536) { src = wv; dst = wvb; off = i - 8430080; }
  else                  { src = wp; dst = wpb; off = i - 8577536; }
  float4 v = *(const float4*)(src + off);
  ushort4 o;
  o.x = f2bf(v.x); o.y = f2bf(v.y); o.z = f2bf(v.z); o.w = f2bf(v.w);
  *(ushort4*)(dst + off) = o;
}

// ---------------- K1: att = softmax_q(x @ w_qkv^T * scale) ----------------
// grid 1024, block 256. M-tile 64, per-head N=81. Coalesced dword stores via LDS tile.
__global__ __launch_bounds__(256) void att_kernel(const unsigned short* __restrict__ xb,
                                                  const unsigned short* __restrict__ wqb,
                                                  unsigned short* __restrict__ attb) {
  __shared__ unsigned short A[64 * 130];    // 16.6 KB
  __shared__ unsigned short Bl[96 * 130];   // 25.0 KB (attile aliased on top)
  __shared__ float lg[64][84];              // 21.5 KB
  const int t = threadIdx.x;
  const long m0 = (long)blockIdx.x * 64;
  for (int i = t; i < 1024; i += 256) {
    int row = i >> 4, seg = i & 15;
    const uint4 v = *(const uint4*)(xb + (m0 + row) * 128 + seg * 8);
    unsigned* d = (unsigned*)(A + row * 130 + seg * 8);
    d[0] = v.x; d[1] = v.y; d[2] = v.z; d[3] = v.w;
  }
  const int wv = t >> 6, lane = t & 63, qd = lane >> 4, l15 = lane & 15;
  __syncthreads();
  bf16x8 af[4];
#pragma unroll
  for (int kk = 0; kk < 4; kk++)
    af[kk] = ldsFrag(A + (wv * 16 + l15) * 130 + kk * 32 + qd * 8);

  unsigned short* attile = Bl;              // [64][9][10] shorts, aliased
  for (int h = 0; h < 4; h++) {
    __syncthreads();   // prev iter's attile store readers done
    for (int i = t; i < 1296; i += 256) {   // stage 81 rows of w_qkv[h]
      int row = i >> 4, seg = i & 15;
      const uint4 v = *(const uint4*)(wqb + (long)(h * 81 + row) * 128 + seg * 8);
      unsigned* d = (unsigned*)(Bl + row * 130 + seg * 8);
      d[0] = v.x; d[1] = v.y; d[2] = v.z; d[3] = v.w;
    }
    __syncthreads();
    f32x4 acc[6] = {};
#pragma unroll
    for (int kk = 0; kk < 4; kk++)
#pragma unroll
      for (int tn = 0; tn < 6; tn++) {
        bf16x8 bf = ldsFrag(Bl + (tn * 16 + l15) * 130 + kk * 32 + qd * 8);
        acc[tn] = __builtin_amdgcn_mfma_f32_16x16x32_bf16(af[kk], bf, acc[tn], 0, 0, 0);
      }
#pragma unroll
    for (int tn = 0; tn < 6; tn++)
#pragma unroll
      for (int r = 0; r < 4; r++) {
        int col = tn * 16 + l15;                     // C/D: col=lane&15, row=quad*4+reg
        if (col < 81) lg[wv * 16 + qd * 4 + r][col] = acc[tn][r];
      }
    __syncthreads();
    for (int g = t; g < 576; g += 256) {             // 64 rows x 9 p-groups
      int row = g / 9, p = g % 9;
      const float* L = &lg[row][p * 9];
      float mx = L[0];
#pragma unroll
      for (int q = 1; q < 9; q++) mx = fmaxf(mx, L[q]);
      float e[9], s = 0.f;
#pragma unroll
      for (int q = 0; q < 9; q++) { e[q] = __expf((L[q] - mx) * SCALE); s += e[q]; }
      float inv = 1.f / s;
#pragma unroll
      for (int q = 0; q < 9; q++) attile[row * 90 + q * 10 + p] = f2bf(e[q] * inv);
    }
    __syncthreads();
    // coalesced store: per (n,q): 5 dwords -> attb[n][q][h*10 ..]
#pragma unroll
    for (int k = 0; k < 12; k++) {
      int i = t + k * 256;
      if (i < 2880) {
        int n = i / 45, r = i - n * 45, q = r / 5, j = r - q * 5;
        ((unsigned*)attb)[(m0 + n) * 180 + q * 20 + h * 5 + j] =
            ((const unsigned*)attile)[n * 45 + q * 5 + j];
      }
    }
  }
}

// ---------------- K2: U[q][n][c] = x[n] . w_v[q][c][:] ----------------
__global__ __launch_bounds__(256) void ugemm_kernel(const unsigned short* __restrict__ xb,
                                                    const unsigned short* __restrict__ wvb,
                                                    unsigned short* __restrict__ U) {
  __shared__ unsigned short A[64 * 130];    // 16.6 KB
  __shared__ unsigned short Bl[128 * 130];  // 33.3 KB
  const int t = threadIdx.x;
  const long m0 = (long)blockIdx.x * 64;
  for (int i = t; i < 1024; i += 256) {
    int row = i >> 4, seg = i & 15;
    const uint4 v = *(const uint4*)(xb + (m0 + row) * 128 + seg * 8);
    unsigned* d = (unsigned*)(A + row * 130 + seg * 8);
    d[0] = v.x; d[1] = v.y; d[2] = v.z; d[3] = v.w;
  }
  const int wv = t >> 6, lane = t & 63, qd = lane >> 4, l15 = lane & 15;
  __syncthreads();
  bf16x8 af[4];
#pragma unroll
  for (int kk = 0; kk < 4; kk++)
    af[kk] = ldsFrag(A + (wv * 16 + l15) * 130 + kk * 32 + qd * 8);

  for (int q = 0; q < 9; q++) {
    __syncthreads();
    for (int i = t; i < 2048; i += 256) {
      int row = i >> 4, seg = i & 15;
      const uint4 v = *(const uint4*)(wvb + (long)q * 16384 + row * 128 + seg * 8);
      unsigned* d = (unsigned*)(Bl + row * 130 + seg * 8);
      d[0] = v.x; d[1] = v.y; d[2] = v.z; d[3] = v.w;
    }
    __syncthreads();
    f32x4 acc[8] = {};
#pragma unroll
    for (int kk = 0; kk < 4; kk++)
#pragma unroll
      for (int tn = 0; tn < 8; tn++) {
        bf16x8 bf = ldsFrag(Bl + (tn * 16 + l15) * 130 + kk * 32 + qd * 8);
        acc[tn] = __builtin_amdgcn_mfma_f32_16x16x32_bf16(af[kk], bf, acc[tn], 0, 0, 0);
      }
#pragma unroll
    for (int tn = 0; tn < 8; tn++)
#pragma unroll
      for (int r = 0; r < 4; r++) {
        int row = wv * 16 + qd * 4 + r;
        int col = tn * 16 + l15;
        U[((size_t)q * 65536 + m0 + row) * 128 + col] = f2bf(acc[tn][r]);
      }
  }
}

// ---------------- K3: fold (att x U gather) + proj ----------------
// grid (16,16,4), block 256. Wave = 16 locations x 4 heads (2-way-free LDS banks).
__global__ __launch_bounds__(256, 4) void av_kernel(const unsigned short* __restrict__ U,
                                                    const unsigned short* __restrict__ attb,
                                                    const unsigned short* __restrict__ wpb,
                                                    float* __restrict__ out) {
  __shared__ unsigned short S[100 * 130];   // 26.0 KB ; reused as ybf for proj
  __shared__ unsigned short aLs[100 * 40];  // 8.0 KB
  const int t = threadIdx.x;
  const int bb = blockIdx.z;
  const int r0 = blockIdx.y * 8, c0 = blockIdx.x * 8;
  const int l15 = t & 15, h = (t >> 4) & 3, wv = t >> 6;
  const int n = wv * 16 + l15, lr = n >> 3, lc = n & 7, h10 = h * 10;
  const long nb = (long)bb * 16384;

  v2f y2[16];
#pragma unroll
  for (int i = 0; i < 16; i++) y2[i] = (v2f){0.f, 0.f};

  uint4 sv[7];
  unsigned avv[8];

#define LOAD_S(qq)                                                                        \
  {                                                                                       \
    const int oqr = (qq) / 3 - 1, oqc = (qq) % 3 - 1;                                     \
    _Pragma("unroll") for (int k = 0; k < 7; k++) {                                       \
      int i = t + k * 256;                                                                \
      if (i < 1600) {                                                                     \
        int row = i >> 4, seg = i & 15;                                                   \
        int gr = r0 - 1 + row / 10 + oqr, gc = c0 - 1 + row % 10 + oqc;                   \
        sv[k] = (gr >= 0 && gr < 128 && gc >= 0 && gc < 128)                              \
                    ? *(const uint4*)(U + ((size_t)(qq) * 65536 + nb + gr * 128 + gc) *   \
                                              128 + seg * 8)                              \
                    : make_uint4(0, 0, 0, 0);                                             \
      }                                                                                   \
    }                                                                                     \
  }
#define LOAD_A(qq)                                                                        \
  {                                                                                       \
    _Pragma("unroll") for (int k = 0; k < 8; k++) {                                       \
      int i = t + k * 256;                                                                \
      if (i < 2000) {                                                                     \
        int row = i / 20, j = i - row * 20;                                               \
        int gr = r0 - 1 + row / 10, gc = c0 - 1 + row % 10;                               \
        avv[k] = (gr >= 0 && gr < 128 && gc >= 0 && gc < 128)                             \
                     ? ((const unsigned*)attb)[(size_t)(nb + gr * 128 + gc) * 180 +       \
                                               (qq) * 20 + j]                             \
                     : 0u;                                                                \
      }                                                                                   \
    }                                                                                     \
  }

  LOAD_S(0)
  LOAD_A(0)
  for (int q = 0; q < 9; q++) {
    __syncthreads();      // prev fold's LDS readers done
    // regs -> LDS
#pragma unroll
    for (int k = 0; k < 7; k++) {
      int i = t + k * 256;
      if (i < 1600) {
        int row = i >> 4, seg = i & 15;
        unsigned* d = (unsigned*)(S + row * 130 + seg * 8);
        d[0] = sv[k].x; d[1] = sv[k].y; d[2] = sv[k].z; d[3] = sv[k].w;
      }
    }
#pragma unroll
    for (int k = 0; k < 8; k++) {
      int i = t + k * 256;
      if (i < 2000) {
        int row = i / 20, j = i - row * 20;
        ((unsigned*)aLs)[row * 20 + j] = avv[k];
      }
    }
    __syncthreads();
    if (q < 8) { LOAD_S(q + 1) LOAD_A(q + 1) }   // overlap with fold below

#pragma unroll
    for (int p = 0; p < 9; p++) {
      const int em = 1 - p / 3, ec = 1 - p % 3;
      const int ml = (lr + em + 1) * 10 + (lc + ec + 1);
      const float a = bf2f(aLs[ml * 40 + h10 + p]);
      const v2f a2 = {a, a};
      const unsigned* Sr = (const unsigned*)S + ml * 65 + (h << 4);
#pragma unroll
      for (int d = 0; d < 16; d++) {
        unsigned u = Sr[d];
        v2f xv;
        xv.x = __uint_as_float(u << 16);
        xv.y = __uint_as_float(u & 0xffff0000u);
        y2[d] += a2 * xv;
      }
    }
  }

  // ---- proj: out[n][o] = sum_c y[n][c] * wp[o][c]; wp frags straight from L2 ----
  __syncthreads();
  unsigned short* yb = S;                   // alias
  {
    unsigned* dst = (unsigned*)(yb + n * 130) + (h << 4);
#pragma unroll
    for (int d = 0; d < 16; d++)
      dst[d] = (unsigned)f2bf(y2[d].x) | ((unsigned)f2bf(y2[d].y) << 16);
  }
  __syncthreads();
  const int lane = t & 63, qd = lane >> 4;
  f32x4 pacc[8] = {};
#pragma unroll
  for (int kk = 0; kk < 4; kk++) {
    bf16x8 afr = ldsFrag(yb + (wv * 16 + l15) * 130 + kk * 32 + qd * 8);
#pragma unroll
    for (int tn = 0; tn < 8; tn++) {
      bf16x8 bfr = ldg8(wpb + (tn * 16 + l15) * 128 + kk * 32 + qd * 8);
      pacc[tn] = __builtin_amdgcn_mfma_f32_16x16x32_bf16(afr, bfr, pacc[tn], 0, 0, 0);
    }
  }
#pragma unroll
  for (int tn = 0; tn < 8; tn++)
#pragma unroll
    for (int r = 0; r < 4; r++) {
      int nl = wv * 16 + qd * 4 + r;
      int col = tn * 16 + l15;
      out[(nb + (r0 + (nl >> 3)) * 128 + (c0 + (nl & 7))) * 128 + col] = pacc[tn][r];
    }
}

extern "C" void kernel_launch(void* const* d_in, const int* in_sizes, int n_in,
                              void* d_out, int out_size, void* d_ws, size_t ws_size,
                              hipStream_t stream) {
  const float* x  = (const float*)d_in[0];
  const float* wq = (const float*)d_in[1];
  const float* wv = (const float*)d_in[2];
  const float* wp = (const float*)d_in[3];
  char* w = (char*)d_ws;
  unsigned short* xb   = (unsigned short*)w;                  // 16,777,216 B
  unsigned short* U    = (unsigned short*)(w + 16777216);     // 150,994,944 B
  unsigned short* attb = (unsigned short*)(w + 167772160);    // 47,185,920 B
  unsigned short* wqb  = (unsigned short*)(w + 214958080);    // 82,944 B
  unsigned short* wvb  = wqb + 41472;                         // 294,912 B
  unsigned short* wpb  = wvb + 147456;                        // 32,768 B

  cvt_kernel<<<8393, 256, 0, stream>>>(x, wq, wv, wp, xb, wqb, wvb, wpb);
  att_kernel<<<1024, 256, 0, stream>>>(xb, wqb, attb);
  ugemm_kernel<<<1024, 256, 0, stream>>>(xb, wvb, U);
  dim3 g3(16, 16, 4);
  av_kernel<<<g3, 256, 0, stream>>>(U, attb, wpb, (float*)d_out);
}

// Round 4
// 248.365 us; speedup vs baseline: 22.1665x; 1.3455x over previous
//
#include <hip/hip_runtime.h>

// CSA bf16-MFMA pipeline v4. B=4 H=W=128 C=128 heads=4 K2=9, hd=32.
// U is no longer materialized: av_kernel computes V_q per-tile via MFMA from the
// 12x12 x-halo in LDS (V^T layout: lane owns 4 consecutive channels of one location).
// ws: xb[65536][128] | attb[65536][9][40] (h*10+p) | wqkvb | wvb | wpb   (all bf16)

typedef short bf16x8 __attribute__((ext_vector_type(8)));
typedef float f32x4  __attribute__((ext_vector_type(4)));
typedef float v2f    __attribute__((ext_vector_type(2)));

#define SCALE 0.17677669529663687f   // hd^-0.5

__device__ __forceinline__ unsigned short f2bf(float f) {
  unsigned u = __float_as_uint(f);
  u = (u + 0x7fffu + ((u >> 16) & 1u)) >> 16;   // RNE
  return (unsigned short)u;
}
__device__ __forceinline__ float bf2f(unsigned short s) {
  return __uint_as_float(((unsigned)s) << 16);
}
__device__ __forceinline__ bf16x8 ldsFrag(const unsigned short* p) {  // p 4B-aligned
  union { bf16x8 v; unsigned u[4]; } r;
  const unsigned* s = (const unsigned*)p;
  r.u[0] = s[0]; r.u[1] = s[1]; r.u[2] = s[2]; r.u[3] = s[3];
  return r.v;
}
__device__ __forceinline__ bf16x8 ldg8(const unsigned short* p) {     // p 16B-aligned global
  union { bf16x8 v; uint4 u; } r;
  r.u = *(const uint4*)p;
  return r.v;
}

// ---------------- K0: fp32 -> bf16 conversions ----------------
__global__ __launch_bounds__(256) void cvt_kernel(const float* __restrict__ x,
                                                  const float* __restrict__ wq,
                                                  const float* __restrict__ wv,
                                                  const float* __restrict__ wp,
                                                  unsigned short* __restrict__ xb,
                                                  unsigned short* __restrict__ wqb,
                                                  unsigned short* __restrict__ wvb,
                                                  unsigned short* __restrict__ wpb) {
  long i = ((long)blockIdx.x * 256 + threadIdx.x) * 4;
  if (i >= 8593920) return;
  const float* src; unsigned short* dst; long off;
  if (i < 8388608)      { src = x;  dst = xb;  off = i; }
  else if (i < 8430080) { src = wq; dst = wqb; off = i - 8388608; }
  else if (i < 8577536) { src = wv; dst = wvb; off = i - 8430080; }
  else                  { src = wp; dst = wpb; off = i - 8577536; }
  float4 v = *(const float4*)(src + off);
  ushort4 o;
  o.x = f2bf(v.x); o.y = f2bf(v.y); o.z = f2bf(v.z); o.w = f2bf(v.w);
  *(ushort4*)(dst + off) = o;
}

// ---------------- K1: att = softmax_q(x @ w_qkv^T * scale) ----------------
__global__ __launch_bounds__(256) void att_kernel(const unsigned short* __restrict__ xb,
                                                  const unsigned short* __restrict__ wqb,
                                                  unsigned short* __restrict__ attb) {
  __shared__ unsigned short A[64 * 130];    // 16.6 KB
  __shared__ unsigned short Bl[96 * 130];   // 25.0 KB (attile aliased on top)
  __shared__ float lg[64][84];              // 21.5 KB
  const int t = threadIdx.x;
  const long m0 = (long)blockIdx.x * 64;
  for (int i = t; i < 1024; i += 256) {
    int row = i >> 4, seg = i & 15;
    const uint4 v = *(const uint4*)(xb + (m0 + row) * 128 + seg * 8);
    unsigned* d = (unsigned*)(A + row * 130 + seg * 8);
    d[0] = v.x; d[1] = v.y; d[2] = v.z; d[3] = v.w;
  }
  const int wv = t >> 6, lane = t & 63, qd = lane >> 4, l15 = lane & 15;
  __syncthreads();
  bf16x8 af[4];
#pragma unroll
  for (int kk = 0; kk < 4; kk++)
    af[kk] = ldsFrag(A + (wv * 16 + l15) * 130 + kk * 32 + qd * 8);

  unsigned short* attile = Bl;              // [64][9][10] shorts, aliased
  for (int h = 0; h < 4; h++) {
    __syncthreads();
    for (int i = t; i < 1296; i += 256) {   // stage 81 rows of w_qkv[h]
      int row = i >> 4, seg = i & 15;
      const uint4 v = *(const uint4*)(wqb + (long)(h * 81 + row) * 128 + seg * 8);
      unsigned* d = (unsigned*)(Bl + row * 130 + seg * 8);
      d[0] = v.x; d[1] = v.y; d[2] = v.z; d[3] = v.w;
    }
    __syncthreads();
    f32x4 acc[6] = {};
#pragma unroll
    for (int kk = 0; kk < 4; kk++)
#pragma unroll
      for (int tn = 0; tn < 6; tn++) {
        bf16x8 bf = ldsFrag(Bl + (tn * 16 + l15) * 130 + kk * 32 + qd * 8);
        acc[tn] = __builtin_amdgcn_mfma_f32_16x16x32_bf16(af[kk], bf, acc[tn], 0, 0, 0);
      }
#pragma unroll
    for (int tn = 0; tn < 6; tn++)
#pragma unroll
      for (int r = 0; r < 4; r++) {
        int col = tn * 16 + l15;
        if (col < 81) lg[wv * 16 + qd * 4 + r][col] = acc[tn][r];
      }
    __syncthreads();
    for (int g = t; g < 576; g += 256) {
      int row = g / 9, p = g % 9;
      const float* L = &lg[row][p * 9];
      float mx = L[0];
#pragma unroll
      for (int q = 1; q < 9; q++) mx = fmaxf(mx, L[q]);
      float e[9], s = 0.f;
#pragma unroll
      for (int q = 0; q < 9; q++) { e[q] = __expf((L[q] - mx) * SCALE); s += e[q]; }
      float inv = 1.f / s;
#pragma unroll
      for (int q = 0; q < 9; q++) attile[row * 90 + q * 10 + p] = f2bf(e[q] * inv);
    }
    __syncthreads();
#pragma unroll
    for (int k = 0; k < 12; k++) {
      int i = t + k * 256;
      if (i < 2880) {
        int n = i / 45, r = i - n * 45, q = r / 5, j = r - q * 5;
        ((unsigned*)attb)[(m0 + n) * 180 + q * 20 + h * 5 + j] =
            ((const unsigned*)attile)[n * 45 + q * 5 + j];
      }
    }
  }
}

// ---------------- K2: fused V-MFMA + fold + proj ----------------
// grid (16,16,4), block 256 = 4 waves. Per q: V_q^T = w_v[q] @ x_shifted^T into S,
// then fold-gather into y. LDS 71.4 KB -> 2 blocks/CU.
__global__ __launch_bounds__(256, 2) void av_kernel(const unsigned short* __restrict__ xb,
                                                    const unsigned short* __restrict__ wvb,
                                                    const unsigned short* __restrict__ attb,
                                                    const unsigned short* __restrict__ wpb,
                                                    float* __restrict__ out) {
  __shared__ unsigned short A[144 * 130];   // 37.4 KB : x halo 12x12 (row-major, +2 pad)
  __shared__ unsigned short S[100 * 130];   // 26.0 KB : V_q for 10x10 halo
  __shared__ unsigned short aLs[100 * 40];  // 8.0 KB  : att slice for q
  const int t = threadIdx.x;
  const int bb = blockIdx.z;
  const int r0 = blockIdx.y * 8, c0 = blockIdx.x * 8;
  const int l15 = t & 15, h = (t >> 4) & 3, wvi = t >> 6;   // h == quad(qd) of lane
  const int n = wvi * 16 + l15, lr = n >> 3, lc = n & 7, h10 = h * 10;
  const long nb = (long)bb * 16384;

  // per-thread location geometry for the 7 N-tiles (ml = nt*16 + l15)
  int mlr_[7], mlc_[7];
#pragma unroll
  for (int nt = 0; nt < 7; nt++) {
    int ml = nt * 16 + l15;
    mlr_[nt] = ml / 10; mlc_[nt] = ml % 10;
  }

  // ---- stage x halo 12x12 -> A ----
#pragma unroll
  for (int k = 0; k < 9; k++) {
    int i = t + k * 256;                    // 2304 = 144 rows x 16 seg
    int row = i >> 4, seg = i & 15;
    int gr = r0 - 2 + row / 12, gc = c0 - 2 + row % 12;
    uint4 v = make_uint4(0, 0, 0, 0);
    if (gr >= 0 && gr < 128 && gc >= 0 && gc < 128)
      v = *(const uint4*)(xb + (nb + gr * 128 + gc) * 128 + seg * 8);
    unsigned* d = (unsigned*)(A + row * 130 + seg * 8);
    d[0] = v.x; d[1] = v.y; d[2] = v.z; d[3] = v.w;
  }

  v2f y2[16];
#pragma unroll
  for (int i = 0; i < 16; i++) y2[i] = (v2f){0.f, 0.f};

  unsigned avv[8];
  bf16x8 wvf[2][4];

#define LOAD_A(qq)                                                                        \
  {                                                                                       \
    _Pragma("unroll") for (int k = 0; k < 8; k++) {                                       \
      int i = t + k * 256;                                                                \
      if (i < 2000) {                                                                     \
        int row = i / 20, j = i - row * 20;                                               \
        int gr = r0 - 1 + row / 10, gc = c0 - 1 + row % 10;                               \
        avv[k] = (gr >= 0 && gr < 128 && gc >= 0 && gc < 128)                             \
                     ? ((const unsigned*)attb)[(size_t)(nb + gr * 128 + gc) * 180 +       \
                                               (qq) * 20 + j]                             \
                     : 0u;                                                                \
      }                                                                                   \
    }                                                                                     \
  }
#define LOAD_WV(qq)                                                                       \
  {                                                                                       \
    _Pragma("unroll") for (int m = 0; m < 2; m++)                                         \
    _Pragma("unroll") for (int kk = 0; kk < 4; kk++)                                      \
      wvf[m][kk] = ldg8(wvb + ((size_t)(qq) * 128 + (wvi * 2 + m) * 16 + l15) * 128 +     \
                        kk * 32 + (h << 3));                                              \
  }

  LOAD_A(0)
  LOAD_WV(0)

  for (int q = 0; q < 9; q++) {
    const int oqr = q / 3 - 1, oqc = q % 3 - 1;
    __syncthreads();                        // A staged / fold(q-1) readers done

    // att regs -> aLs
#pragma unroll
    for (int k = 0; k < 8; k++) {
      int i = t + k * 256;
      if (i < 2000) {
        int row = i / 20, j = i - row * 20;
        ((unsigned*)aLs)[row * 20 + j] = avv[k];
      }
    }

    // ---- V_q^T via MFMA: D[row=channel][col=location] ----
    f32x4 acc[2][7];
#pragma unroll
    for (int m = 0; m < 2; m++)
#pragma unroll
      for (int nt = 0; nt < 7; nt++) acc[m][nt] = (f32x4){0.f, 0.f, 0.f, 0.f};
#pragma unroll
    for (int nt = 0; nt < 7; nt++) {
      int xr = (mlr_[nt] + oqr + 1) * 12 + (mlc_[nt] + oqc + 1);
      xr = xr > 143 ? 143 : xr;             // pad rows (ml>=100) clamp
      bf16x8 bx[4];
#pragma unroll
      for (int kk = 0; kk < 4; kk++)
        bx[kk] = ldsFrag(A + xr * 130 + kk * 32 + (h << 3));
#pragma unroll
      for (int m = 0; m < 2; m++)
#pragma unroll
        for (int kk = 0; kk < 4; kk++)
          acc[m][nt] = __builtin_amdgcn_mfma_f32_16x16x32_bf16(wvf[m][kk], bx[kk],
                                                               acc[m][nt], 0, 0, 0);
    }
    // store V^T tiles: lane owns channels mt*16+h*4..+3 of location nt*16+l15
#pragma unroll
    for (int m = 0; m < 2; m++)
#pragma unroll
      for (int nt = 0; nt < 7; nt++) {
        int loc = nt * 16 + l15;
        if (loc < 100) {
          int mt = wvi * 2 + m;
          unsigned u0 = (unsigned)f2bf(acc[m][nt][0]) | ((unsigned)f2bf(acc[m][nt][1]) << 16);
          unsigned u1 = (unsigned)f2bf(acc[m][nt][2]) | ((unsigned)f2bf(acc[m][nt][3]) << 16);
          unsigned* d = (unsigned*)S + loc * 65 + mt * 8 + h * 2;
          d[0] = u0; d[1] = u1;
        }
      }
    __syncthreads();
    if (q < 8) { LOAD_A(q + 1) LOAD_WV(q + 1) }   // overlap with fold

    // ---- fold: y[n,c] += att[n',h,p,q] * V_q[n'] ----
#pragma unroll
    for (int p = 0; p < 9; p++) {
      const int em = 1 - p / 3, ec = 1 - p % 3;
      const int ml = (lr + em + 1) * 10 + (lc + ec + 1);
      const float a = bf2f(aLs[ml * 40 + h10 + p]);
      const v2f a2 = {a, a};
      const unsigned* Sr = (const unsigned*)S + ml * 65 + (h << 4);
#pragma unroll
      for (int d = 0; d < 16; d++) {
        unsigned u = Sr[d];
        v2f xv;
        xv.x = __uint_as_float(u << 16);
        xv.y = __uint_as_float(u & 0xffff0000u);
        y2[d] += a2 * xv;
      }
    }
  }

  // ---- proj: out[n][o] = sum_c y[n][c] * wp[o][c] (yb aliases A) ----
  unsigned short* yb = A;
  {
    unsigned* dst = (unsigned*)(yb + n * 130) + (h << 4);
#pragma unroll
    for (int d = 0; d < 16; d++)
      dst[d] = (unsigned)f2bf(y2[d].x) | ((unsigned)f2bf(y2[d].y) << 16);
  }
  __syncthreads();
  f32x4 pacc[8] = {};
#pragma unroll
  for (int kk = 0; kk < 4; kk++) {
    bf16x8 afr = ldsFrag(yb + (wvi * 16 + l15) * 130 + kk * 32 + (h << 3));
#pragma unroll
    for (int tn = 0; tn < 8; tn++) {
      bf16x8 bfr = ldg8(wpb + (tn * 16 + l15) * 128 + kk * 32 + (h << 3));
      pacc[tn] = __builtin_amdgcn_mfma_f32_16x16x32_bf16(afr, bfr, pacc[tn], 0, 0, 0);
    }
  }
#pragma unroll
  for (int tn = 0; tn < 8; tn++)
#pragma unroll
    for (int r = 0; r < 4; r++) {
      int nl = wvi * 16 + h * 4 + r;
      int col = tn * 16 + l15;
      out[(nb + (r0 + (nl >> 3)) * 128 + (c0 + (nl & 7))) * 128 + col] = pacc[tn][r];
    }
}

extern "C" void kernel_launch(void* const* d_in, const int* in_sizes, int n_in,
                              void* d_out, int out_size, void* d_ws, size_t ws_size,
                              hipStream_t stream) {
  const float* x  = (const float*)d_in[0];
  const float* wq = (const float*)d_in[1];
  const float* wv = (const float*)d_in[2];
  const float* wp = (const float*)d_in[3];
  char* w = (char*)d_ws;
  unsigned short* xb   = (unsigned short*)w;                  // 16,777,216 B
  unsigned short* attb = (unsigned short*)(w + 16777216);     // 47,185,920 B
  unsigned short* wqb  = (unsigned short*)(w + 63963136);     // 82,944 B
  unsigned short* wvb  = wqb + 41472;                         // 294,912 B
  unsigned short* wpb  = wvb + 147456;                        // 32,768 B

  cvt_kernel<<<8393, 256, 0, stream>>>(x, wq, wv, wp, xb, wqb, wvb, wpb);
  att_kernel<<<1024, 256, 0, stream>>>(xb, wqb, attb);
  dim3 g3(16, 16, 4);
  av_kernel<<<g3, 256, 0, stream>>>(xb, wvb, attb, wpb, (float*)d_out);
}